// Round 2
// baseline (87.880 us; speedup 1.0000x reference)
//
#include <hip/hip_runtime.h>
#include <math.h>

// Problem constants: B=32, E=1024, H=1024, N=128, L=64, K=8
#define NB 32
#define NE 1024
#define NH 1024
#define NN 128
#define NL 64
#define NK 8
#define GS 8   // g-chunks for qk partial sums

// ---------------------------------------------------------------------------
// rowdot8: one wave computes dot(W[o,:], A[b,:]) + bias[o] for 8 consecutive b
// ---------------------------------------------------------------------------
template <int D>
__device__ void rowdot8(const float* __restrict__ A, const float* __restrict__ W,
                        const float* __restrict__ bias, float* __restrict__ C,
                        int wid) {
    int lane = threadIdx.x & 63;
    int o  = wid >> 2;          // 0..1023
    int b0 = (wid & 3) * 8;     // batch group of 8
    const float4* Wr = (const float4*)(W + (size_t)o * D);
    const float4* Ar[8];
#pragma unroll
    for (int i = 0; i < 8; ++i) Ar[i] = (const float4*)(A + (size_t)(b0 + i) * D);
    float acc[8] = {0.f, 0.f, 0.f, 0.f, 0.f, 0.f, 0.f, 0.f};
#pragma unroll
    for (int c = 0; c < D / 256; ++c) {
        float4 w4 = Wr[c * 64 + lane];
#pragma unroll
        for (int i = 0; i < 8; ++i) {
            float4 a = Ar[i][c * 64 + lane];
            acc[i] += w4.x * a.x + w4.y * a.y + w4.z * a.z + w4.w * a.w;
        }
    }
#pragma unroll
    for (int s = 32; s; s >>= 1)
#pragma unroll
        for (int i = 0; i < 8; ++i) acc[i] += __shfl_down(acc[i], s, 64);
    if (lane == 0) {
        float bb = bias[o];
#pragma unroll
        for (int i = 0; i < 8; ++i) C[(size_t)(b0 + i) * NH + o] = acc[i] + bb;
    }
}

// ---------------------------------------------------------------------------
// FAT1: blocks [0,1024): scores[b,n] = cache_keys[b,n,:]·inputs[b,:]
//       blocks [1024,2048): query = inputs @ Wq^T + bq
// ---------------------------------------------------------------------------
__global__ void fat1_kernel(const float* __restrict__ cache_keys,
                            const float* __restrict__ inputs,
                            const float* __restrict__ Wq,
                            const float* __restrict__ bq,
                            float* __restrict__ scores,
                            float* __restrict__ query) {
    if (blockIdx.x < 1024) {
        int wid  = blockIdx.x * 4 + (threadIdx.x >> 6);   // 0..4095
        int lane = threadIdx.x & 63;
        int b = wid >> 7, n = wid & 127;
        const float4* ck = (const float4*)(cache_keys + ((size_t)b * NN + n) * NE);
        const float4* in = (const float4*)(inputs + (size_t)b * NE);
        float acc = 0.f;
#pragma unroll
        for (int c = 0; c < 4; ++c) {
            float4 a = ck[c * 64 + lane];
            float4 x = in[c * 64 + lane];
            acc += a.x * x.x + a.y * x.y + a.z * x.z + a.w * x.w;
        }
#pragma unroll
        for (int s = 32; s; s >>= 1) acc += __shfl_down(acc, s, 64);
        if (lane == 0) scores[b * NN + n] = acc;
    } else {
        int wid = (blockIdx.x - 1024) * 4 + (threadIdx.x >> 6);  // 0..4095
        rowdot8<1024>(inputs, Wq, bq, query, wid);
    }
}

// ---------------------------------------------------------------------------
// FAT2: blocks [0,32): pqk partials; blocks [32,64): per-batch top-8 + softmax
// pqk[gs][b][h] = sum_{g in gs-chunk of 128} query[b,g] * Wk[g,h]
// (bk dropped: q·bk is constant over l -> cancels in the l-softmax)
// ---------------------------------------------------------------------------
__global__ void fat2_kernel(const float* __restrict__ query,
                            const float* __restrict__ Wk,
                            const float* __restrict__ scores,
                            float* __restrict__ pqk,
                            int* __restrict__ top_idx,
                            float* __restrict__ weights) {
    __shared__ float qv[8 * 128];   // 8 batches x 128 g values
    __shared__ float tv[NK];
    int t = threadIdx.x;
    if (blockIdx.x < 32) {
        int gs = blockIdx.x & 7;    // g-chunk
        int bq = blockIdx.x >> 3;   // batch group of 8
        {
            int bb = t >> 5, gg4 = t & 31;
            const float4* q4 = (const float4*)(query + (size_t)(bq * 8 + bb) * NH + gs * 128);
            ((float4*)qv)[t] = q4[gg4];
        }
        __syncthreads();
        const float4* Wr = (const float4*)Wk;
        float4 acc[8];
#pragma unroll
        for (int i = 0; i < 8; ++i) acc[i] = make_float4(0.f, 0.f, 0.f, 0.f);
        for (int gg = 0; gg < 128; ++gg) {
            int g = gs * 128 + gg;
            float4 w = Wr[(size_t)g * 256 + t];
#pragma unroll
            for (int bb = 0; bb < 8; ++bb) {
                float qq = qv[bb * 128 + gg];
                acc[bb].x += qq * w.x; acc[bb].y += qq * w.y;
                acc[bb].z += qq * w.z; acc[bb].w += qq * w.w;
            }
        }
#pragma unroll
        for (int bb = 0; bb < 8; ++bb)
            ((float4*)pqk)[((size_t)gs * NB + bq * 8 + bb) * 256 + t] = acc[bb];
    } else {
        int b = blockIdx.x - 32;
        if (t < 64) {
            float s0 = scores[b * NN + t];
            float s1 = scores[b * NN + 64 + t];
            for (int i = 0; i < NK; ++i) {
                float v = s0; int idx = t;
                if (s1 > v) { v = s1; idx = t + 64; }
#pragma unroll
                for (int s = 1; s < 64; s <<= 1) {
                    float ov = __shfl_xor(v, s, 64);
                    int   oi = __shfl_xor(idx, s, 64);
                    if (ov > v || (ov == v && oi < idx)) { v = ov; idx = oi; }
                }
                if (t == 0) { tv[i] = v; top_idx[b * NK + i] = idx; }
                if (idx == t)      s0 = -INFINITY;
                if (idx == t + 64) s1 = -INFINITY;
            }
        }
        __syncthreads();
        if (t < NK) {
            float e = expf(tv[t] - tv[0]);   // tv[0] is the max
            float sum = e;
            sum += __shfl_xor(sum, 1, 64);
            sum += __shfl_xor(sum, 2, 64);
            sum += __shfl_xor(sum, 4, 64);
            weights[b * NK + t] = e / sum;
        }
    }
}

// ---------------------------------------------------------------------------
// ATTN (fused, 1024 threads): per (b,k):
//   qk = reduce(pqk); logits[l] = zones[l,:]·qk / sqrt(H); softmax;
//   patt[b][k][h] = weights[b,k] * sum_l attn[l] * zones[l,h]
// ---------------------------------------------------------------------------
__global__ __launch_bounds__(1024)
void attn_kernel(const float* __restrict__ pqk,
                 const float* __restrict__ cache_values,
                 const int* __restrict__ top_idx,
                 const float* __restrict__ weights,
                 float* __restrict__ patt) {
    int b = blockIdx.x >> 3, k = blockIdx.x & 7;
    __shared__ float qk_lds[NH];
    __shared__ float logits[NL];
    __shared__ float coef[NL];
    __shared__ float psum[4 * NH];   // 16 KB: 4 row-quarters x 1024 h
    int t = threadIdx.x;
    if (t < 256) {
        float4 s = make_float4(0.f, 0.f, 0.f, 0.f);
#pragma unroll
        for (int gs = 0; gs < GS; ++gs) {
            float4 p = ((const float4*)pqk)[((size_t)gs * NB + b) * 256 + t];
            s.x += p.x; s.y += p.y; s.z += p.z; s.w += p.w;
        }
        ((float4*)qk_lds)[t] = s;
    }
    __syncthreads();

    int zi = top_idx[b * NK + k];
    const float* zbase = cache_values + (((size_t)b * NN + zi) * NL) * NH;
    int wv = t >> 6, lane = t & 63;
    // phase 1: 16 waves x 4 rows -> logits
#pragma unroll
    for (int r = 0; r < 4; ++r) {
        int l = wv * 4 + r;
        const float4* zr = (const float4*)(zbase + (size_t)l * NH);
        float acc = 0.f;
#pragma unroll
        for (int c = 0; c < 4; ++c) {
            float4 z = zr[c * 64 + lane];
            float4 q = ((const float4*)qk_lds)[c * 64 + lane];
            acc += z.x * q.x + z.y * q.y + z.z * q.z + z.w * q.w;
        }
#pragma unroll
        for (int s = 32; s; s >>= 1) acc += __shfl_down(acc, s, 64);
        if (lane == 0) logits[l] = acc * 0.03125f;   // 1/sqrt(1024)
    }
    __syncthreads();
    // phase 2: softmax over l (wave 0) folded with retrieval weight
    if (t < 64) {
        float v = logits[t];
        float m = v;
#pragma unroll
        for (int s = 1; s < 64; s <<= 1) m = fmaxf(m, __shfl_xor(m, s, 64));
        float e = expf(v - m);
        float sum = e;
#pragma unroll
        for (int s = 1; s < 64; s <<= 1) sum += __shfl_xor(sum, s, 64);
        coef[t] = weights[b * NK + k] * e / sum;
    }
    __syncthreads();
    // phase 3: weighted row sum; thread (quarter q4, col) sums 16 rows
    {
        int col = t & 255, q4 = t >> 8;
        float4 acc = make_float4(0.f, 0.f, 0.f, 0.f);
#pragma unroll
        for (int r = 0; r < 16; ++r) {
            int l = q4 * 16 + r;
            float c = coef[l];
            float4 z = ((const float4*)(zbase + (size_t)l * NH))[col];
            acc.x += c * z.x; acc.y += c * z.y; acc.z += c * z.z; acc.w += c * z.w;
        }
        ((float4*)psum)[q4 * 256 + col] = acc;
    }
    __syncthreads();
    if (t < 256) {
        float4 s = make_float4(0.f, 0.f, 0.f, 0.f);
#pragma unroll
        for (int q4 = 0; q4 < 4; ++q4) {
            float4 p = ((const float4*)psum)[q4 * 256 + t];
            s.x += p.x; s.y += p.y; s.z += p.z; s.w += p.w;
        }
        ((float4*)patt)[((size_t)b * NK + k) * 256 + t] = s;
    }
}

// ---------------------------------------------------------------------------
// buildF: F[b][0:1024] = sum_k patt[b][k][:], F[b][1024:2048] = inputs[b]
// ---------------------------------------------------------------------------
__global__ void buildF_kernel(const float* __restrict__ patt,
                              const float* __restrict__ inputs,
                              float* __restrict__ F) {
    int gid = blockIdx.x * 256 + threadIdx.x;   // 0..16383 float4s
    int b = gid >> 9, j4 = gid & 511;
    float4 v;
    if (j4 < 256) {
        v = make_float4(0.f, 0.f, 0.f, 0.f);
#pragma unroll
        for (int k = 0; k < NK; ++k) {
            float4 p = ((const float4*)patt)[((size_t)b * NK + k) * 256 + j4];
            v.x += p.x; v.y += p.y; v.z += p.z; v.w += p.w;
        }
    } else {
        v = ((const float4*)(inputs + (size_t)b * NE))[j4 - 256];
    }
    ((float4*)F)[(size_t)b * 512 + j4] = v;
}

// ---------------------------------------------------------------------------
// FINAL: out = F @ Wc^T + bc
// ---------------------------------------------------------------------------
__global__ void final_kernel(const float* __restrict__ F,
                             const float* __restrict__ Wc,
                             const float* __restrict__ bc,
                             float* __restrict__ out) {
    int wid = blockIdx.x * 4 + (threadIdx.x >> 6);  // 0..4095
    rowdot8<2048>(F, Wc, bc, out, wid);
}

// ---------------------------------------------------------------------------
extern "C" void kernel_launch(void* const* d_in, const int* in_sizes, int n_in,
                              void* d_out, int out_size, void* d_ws, size_t ws_size,
                              hipStream_t stream) {
    const float* inputs       = (const float*)d_in[0];
    const float* Wq           = (const float*)d_in[1];
    const float* bq           = (const float*)d_in[2];
    const float* Wk           = (const float*)d_in[3];
    // d_in[4] = bk: cancels in the l-softmax (constant over l)
    const float* Wc           = (const float*)d_in[5];
    const float* bc           = (const float*)d_in[6];
    const float* cache_keys   = (const float*)d_in[7];
    const float* cache_values = (const float*)d_in[8];
    float* out = (float*)d_out;

    float* ws      = (float*)d_ws;
    float* scores  = ws;                       // 4096
    float* query   = scores + 4096;            // 32768
    float* pqk     = query + 32768;            // GS*32*1024 = 262144
    float* patt    = pqk + GS * 32 * 1024;     // 32*8*1024 = 262144
    float* F       = patt + 262144;            // 65536
    float* weights = F + 65536;                // 256
    int*   tidx    = (int*)(weights + 256);    // 256 ints
    (void)ws_size; (void)n_in; (void)in_sizes; (void)out_size;

    fat1_kernel<<<2048, 256, 0, stream>>>(cache_keys, inputs, Wq, bq, scores, query);
    fat2_kernel<<<64, 256, 0, stream>>>(query, Wk, scores, pqk, tidx, weights);
    attn_kernel<<<NB * NK, 1024, 0, stream>>>(pqk, cache_values, tidx, weights, patt);
    buildF_kernel<<<64, 256, 0, stream>>>(patt, inputs, F);
    final_kernel<<<1024, 256, 0, stream>>>(F, Wc, bc, out);
}